// Round 8
// baseline (3436.152 us; speedup 1.0000x reference)
//
#include <hip/hip_runtime.h>

// bf16x3 MFMA: every GEMM runs as hi*hi + hi*lo + lo*hi on
// __builtin_amdgcn_mfma_f32_16x16x32_bf16 (fp32 accumulate).
// This round: counted-vmcnt schedule (T4) on BOTH GEMM kernels, with the
// PROVEN staging pattern (16 rows/wave, XOR-permuted 16B groups).
// Per K-tile: s_waitcnt vmcnt(8) [never 0 in steady state] -> barrier ->
// ds_read all frags to regs -> lgkmcnt(0) -> barrier (buffer free) ->
// stage(kt+2) into freed buffer -> setprio(1) MFMA cluster setprio(0).
// 2 LDS buffers only; in-flight <= 16 GLLs; memory service spans ~2 tiles.
//   gemm3  : 128x128, 256 thr (4 waves 2x2), 64 KiB LDS, 2 blocks/CU.
//   gemm3w : 256x256, 512 thr (8 waves 2x4), 128 KiB LDS, 1 block/CU.

constexpr int Bb = 4, Ss = 2048, Dd = 1024, Ll = 4;
constexpr int BSm = Bb * Ss;          // 8192 rows flattened

typedef short bf16x8 __attribute__((ext_vector_type(8)));
typedef float f32x4  __attribute__((ext_vector_type(4)));
typedef unsigned short us;

__device__ __forceinline__ us bf16_rn(float x) {
    unsigned int u = __float_as_uint(x);
    u += 0x7FFFu + ((u >> 16) & 1u);
    return (us)(u >> 16);
}
__device__ __forceinline__ float bf2f(us h) {
    return __uint_as_float(((unsigned int)h) << 16);
}
__device__ __forceinline__ void fsplit(float v, us& h, us& l) {
    h = bf16_rn(v);
    l = bf16_rn(v - bf2f(h));      // exact subtraction (Sterbenz range)
}

#define GLL(g, l) __builtin_amdgcn_global_load_lds( \
    (const __attribute__((address_space(1))) void*)(g), \
    (__attribute__((address_space(3))) void*)(l), 16, 0, 0)

#define MFMA16(a, b, c) __builtin_amdgcn_mfma_f32_16x16x32_bf16(a, b, c, 0, 0, 0)

// ---------------------------------------------------------------------------
// gemm3: 128x128, BK=32, 256 thr (4 waves 2x2).  Counted-vmcnt schedule.
// A planes [M][K] row-major; B planes [N][K] row-major (W^T).
// ---------------------------------------------------------------------------
template<int OUT, bool HAS_BIAS, int ACT, bool CAUSAL, bool CK, bool ROWSCALE>
__global__ __launch_bounds__(256, 2) void gemm3(
    const us* __restrict__ Ahg, const us* __restrict__ Alg, int lda, long sA,
    const us* __restrict__ Bhg, const us* __restrict__ Blg, int ldb, long sB,
    const float* __restrict__ bias,
    float* __restrict__ Cf, us* __restrict__ Ch, us* __restrict__ Cl,
    int ldc, long sC,
    const float* __restrict__ drec, int K)
{
    __shared__ __align__(16) char lds[2 * 32768];   // 64 KiB

    if (CAUSAL && blockIdx.x > blockIdx.y) return;   // above diagonal: dead
    const int t = threadIdx.x, z = blockIdx.z;
    const int row0 = blockIdx.y * 128, col0 = blockIdx.x * 128;
    Ahg += (size_t)z * sA;  Alg += (size_t)z * sA;
    Bhg += (size_t)z * sB;  Blg += (size_t)z * sB;

    const int srow = t >> 2;
    const int scg  = ((t & 3) ^ ((t >> 3) & 3)) * 8;
    const us* pAh = Ahg + (size_t)(row0 + srow) * lda + scg;
    const us* pAl = Alg + (size_t)(row0 + srow) * lda + scg;
    const us* pBh = Bhg + (size_t)(col0 + srow) * ldb + scg;
    const us* pBl = Blg + (size_t)(col0 + srow) * ldb + scg;
    const size_t a64 = (size_t)64 * lda, b64 = (size_t)64 * ldb;
    const int wb = (t >> 6) * 1024;       // wave-uniform byte base per round

    auto stage = [&](int kt) {
        const int k0 = kt * 32;
        char* base = lds + (kt & 1) * 32768 + wb;
        GLL(pAh + k0,       base + 0 * 8192);
        GLL(pAh + k0 + a64, base + 0 * 8192 + 4096);
        GLL(pAl + k0,       base + 1 * 8192);
        GLL(pAl + k0 + a64, base + 1 * 8192 + 4096);
        GLL(pBh + k0,       base + 2 * 8192);
        GLL(pBh + k0 + b64, base + 2 * 8192 + 4096);
        GLL(pBl + k0,       base + 3 * 8192);
        GLL(pBl + k0 + b64, base + 3 * 8192 + 4096);
    };

    const int ln = t & 63, lr = ln & 15, q = ln >> 4;
    const int w  = t >> 6, wm = w >> 1, wn = w & 1;
    const int xq = (q ^ ((lr >> 1) & 3)) * 16;   // swizzled 16B slot offset
    int offA[4], offB[4];
    #pragma unroll
    for (int m = 0; m < 4; ++m) offA[m] = (wm * 64 + m * 16 + lr) * 64 + xq;
    #pragma unroll
    for (int n = 0; n < 4; ++n) offB[n] = (wn * 64 + n * 16 + lr) * 64 + xq;

    f32x4 acc[4][4] = {};

    int Keff = K;
    if (CK) { int ke = row0 + 128; Keff = ke < K ? ke : K; }
    const int NT = Keff >> 5;             // >= 4 always

    stage(0);
    stage(1);
    for (int kt = 0; kt < NT; ++kt) {
        if (kt < NT - 1) asm volatile("s_waitcnt vmcnt(8)" ::: "memory");
        else             asm volatile("s_waitcnt vmcnt(0)" ::: "memory");
        __builtin_amdgcn_sched_barrier(0);
        __builtin_amdgcn_s_barrier();      // buffer kt ready for all waves
        __builtin_amdgcn_sched_barrier(0);
        const char* base = lds + (kt & 1) * 32768;
        bf16x8 ah[4], al8[4], bh[4], bl8[4];
        #pragma unroll
        for (int m = 0; m < 4; ++m) {
            ah[m]  = *reinterpret_cast<const bf16x8*>(base + 0 * 8192 + offA[m]);
            al8[m] = *reinterpret_cast<const bf16x8*>(base + 1 * 8192 + offA[m]);
        }
        #pragma unroll
        for (int n = 0; n < 4; ++n) {
            bh[n]  = *reinterpret_cast<const bf16x8*>(base + 2 * 8192 + offB[n]);
            bl8[n] = *reinterpret_cast<const bf16x8*>(base + 3 * 8192 + offB[n]);
        }
        asm volatile("s_waitcnt lgkmcnt(0)" ::: "memory");
        __builtin_amdgcn_sched_barrier(0);
        __builtin_amdgcn_s_barrier();      // all reads done: buffer kt free
        if (kt + 2 < NT) stage(kt + 2);    // into freed buffer, 2 tiles early
        __builtin_amdgcn_s_setprio(1);
        #pragma unroll
        for (int n = 0; n < 4; ++n) {
            #pragma unroll
            for (int m = 0; m < 4; ++m) acc[m][n] = MFMA16(ah[m],  bh[n],  acc[m][n]);
            #pragma unroll
            for (int m = 0; m < 4; ++m) acc[m][n] = MFMA16(ah[m],  bl8[n], acc[m][n]);
            #pragma unroll
            for (int m = 0; m < 4; ++m) acc[m][n] = MFMA16(al8[m], bh[n],  acc[m][n]);
        }
        __builtin_amdgcn_s_setprio(0);
    }

    const float* dz = drec + (size_t)z * Ss;   // only read when ROWSCALE
    #pragma unroll
    for (int n = 0; n < 4; ++n) {
        const int col = col0 + wn * 64 + n * 16 + lr;
        const float bv = HAS_BIAS ? bias[col] : 0.0f;
        #pragma unroll
        for (int m = 0; m < 4; ++m) {
            #pragma unroll
            for (int j = 0; j < 4; ++j) {
                const int row = row0 + wm * 64 + m * 16 + 4 * q + j;
                float v = acc[m][n][j] + bv;
                if (ACT == 1)
                    v = 0.5f * v * (1.0f + erff(v * 0.70710678118f));
                if (CAUSAL)
                    v = (col <= row)
                        ? v * (1.0f / (32.0f * (1.0f + sqrtf((float)row))))
                        : 0.0f;
                if (ROWSCALE) v *= dz[row];
                const size_t idx = (size_t)z * sC + (size_t)row * ldc + col;
                if (OUT == 0) {
                    Cf[idx] = v;
                } else {
                    us h_, l_;
                    fsplit(v, h_, l_);
                    Ch[idx] = h_;
                    Cl[idx] = l_;
                }
            }
        }
    }
}

// ---------------------------------------------------------------------------
// gemm3w: 256x256, BK=32, 512 thr = 8 waves (2m x 4n), wave tile 128x64.
// Same staging pattern (2 rounds of 128 rows per panel), counted-vmcnt
// schedule.  LDS per buffer: Ah 16K | Al 16K | Bh 16K | Bl 16K; 2 buf = 128K.
// Panel byte addr of (row R, group g): (R&127)*64 + g*16 + (R>>7)*8192.
// ---------------------------------------------------------------------------
template<int OUT, bool HAS_BIAS, int ACT>
__global__ __launch_bounds__(512, 2) void gemm3w(
    const us* __restrict__ Ahg, const us* __restrict__ Alg, int lda,
    const us* __restrict__ Bhg, const us* __restrict__ Blg, int ldb,
    const float* __restrict__ bias,
    float* __restrict__ Cf, us* __restrict__ Ch, us* __restrict__ Cl,
    int ldc, int K)
{
    __shared__ __align__(16) char lds[2 * 65536];   // 128 KiB

    const int t = threadIdx.x;
    const int row0 = blockIdx.y * 256, col0 = blockIdx.x * 256;

    const int srow = t >> 2;                        // 0..127
    const int scg  = ((t & 3) ^ ((t >> 3) & 3)) * 8;
    const us* pAh = Ahg + (size_t)(row0 + srow) * lda + scg;
    const us* pAl = Alg + (size_t)(row0 + srow) * lda + scg;
    const us* pBh = Bhg + (size_t)(col0 + srow) * ldb + scg;
    const us* pBl = Blg + (size_t)(col0 + srow) * ldb + scg;
    const size_t a128 = (size_t)128 * lda, b128 = (size_t)128 * ldb;
    const int wb = (t >> 6) * 1024;       // wave-uniform byte base per round

    auto stage = [&](int kt) {
        const int k0 = kt * 32;
        char* base = lds + (kt & 1) * 65536 + wb;
        GLL(pAh + k0,        base + 0 * 16384);
        GLL(pAh + k0 + a128, base + 0 * 16384 + 8192);
        GLL(pAl + k0,        base + 1 * 16384);
        GLL(pAl + k0 + a128, base + 1 * 16384 + 8192);
        GLL(pBh + k0,        base + 2 * 16384);
        GLL(pBh + k0 + b128, base + 2 * 16384 + 8192);
        GLL(pBl + k0,        base + 3 * 16384);
        GLL(pBl + k0 + b128, base + 3 * 16384 + 8192);
    };

    const int ln = t & 63, lr = ln & 15, q = ln >> 4;
    const int w  = t >> 6, wm = w >> 2, wn = w & 3;   // 2m x 4n
    const int xq = (q ^ ((lr >> 1) & 3)) * 16;
    int offA[8], offB[4];
    #pragma unroll
    for (int m = 0; m < 8; ++m)          // A rows: wm*128 + m*16 + lr
        offA[m] = (m * 16 + lr) * 64 + xq + wm * 8192;
    #pragma unroll
    for (int n = 0; n < 4; ++n) {        // B rows: wn*64 + n*16 + lr
        const int R = wn * 64 + n * 16 + lr;
        offB[n] = (R & 127) * 64 + xq + (R >> 7) * 8192;
    }

    f32x4 acc[8][4] = {};
    const int NT = K >> 5;

    stage(0);
    stage(1);
    for (int kt = 0; kt < NT; ++kt) {
        if (kt < NT - 1) asm volatile("s_waitcnt vmcnt(8)" ::: "memory");
        else             asm volatile("s_waitcnt vmcnt(0)" ::: "memory");
        __builtin_amdgcn_sched_barrier(0);
        __builtin_amdgcn_s_barrier();      // buffer kt ready for all waves
        __builtin_amdgcn_sched_barrier(0);
        const char* base = lds + (kt & 1) * 65536;
        bf16x8 ah[8], al8[8], bh[4], bl8[4];
        #pragma unroll
        for (int m = 0; m < 8; ++m) {
            ah[m]  = *reinterpret_cast<const bf16x8*>(base + 0 * 16384 + offA[m]);
            al8[m] = *reinterpret_cast<const bf16x8*>(base + 1 * 16384 + offA[m]);
        }
        #pragma unroll
        for (int n = 0; n < 4; ++n) {
            bh[n]  = *reinterpret_cast<const bf16x8*>(base + 2 * 16384 + offB[n]);
            bl8[n] = *reinterpret_cast<const bf16x8*>(base + 3 * 16384 + offB[n]);
        }
        asm volatile("s_waitcnt lgkmcnt(0)" ::: "memory");
        __builtin_amdgcn_sched_barrier(0);
        __builtin_amdgcn_s_barrier();      // all reads done: buffer kt free
        if (kt + 2 < NT) stage(kt + 2);    // into freed buffer, 2 tiles early
        __builtin_amdgcn_s_setprio(1);
        #pragma unroll
        for (int n = 0; n < 4; ++n) {
            #pragma unroll
            for (int m = 0; m < 8; ++m) acc[m][n] = MFMA16(ah[m],  bh[n],  acc[m][n]);
            #pragma unroll
            for (int m = 0; m < 8; ++m) acc[m][n] = MFMA16(ah[m],  bl8[n], acc[m][n]);
            #pragma unroll
            for (int m = 0; m < 8; ++m) acc[m][n] = MFMA16(al8[m], bh[n],  acc[m][n]);
        }
        __builtin_amdgcn_s_setprio(0);
    }

    #pragma unroll
    for (int n = 0; n < 4; ++n) {
        const int col = col0 + wn * 64 + n * 16 + lr;
        const float bv = HAS_BIAS ? bias[col] : 0.0f;
        #pragma unroll
        for (int m = 0; m < 8; ++m) {
            #pragma unroll
            for (int j = 0; j < 4; ++j) {
                const int row = row0 + wm * 128 + m * 16 + 4 * q + j;
                float v = acc[m][n][j] + bv;
                if (ACT == 1)
                    v = 0.5f * v * (1.0f + erff(v * 0.70710678118f));
                const size_t idx = (size_t)row * ldc + col;
                if (OUT == 0) {
                    Cf[idx] = v;
                } else {
                    us h_, l_;
                    fsplit(v, h_, l_);
                    Ch[idx] = h_;
                    Cl[idx] = l_;
                }
            }
        }
    }
}

// ---- elementwise fp32 -> hi/lo split (layer-0 x only) ----------------------
__global__ __launch_bounds__(256) void split_k(
    const float* __restrict__ in, us* __restrict__ oh, us* __restrict__ ol)
{
    const size_t e = (size_t)blockIdx.x * 256 + threadIdx.x;
    float4 v = *reinterpret_cast<const float4*>(in + e * 4);
    ushort4 h4, l4;
    fsplit(v.x, h4.x, l4.x); fsplit(v.y, h4.y, l4.y);
    fsplit(v.z, h4.z, l4.z); fsplit(v.w, h4.w, l4.w);
    *reinterpret_cast<ushort4*>(oh + e * 4) = h4;
    *reinterpret_cast<ushort4*>(ol + e * 4) = l4;
}

// ---- transpose + split: in fp32 [H][W] -> out [W][H] hi/lo bf16 ------------
__global__ __launch_bounds__(256) void tsplit_k(
    const float* __restrict__ in, long sin_,
    us* __restrict__ oh, us* __restrict__ ol, long sout, int H, int W)
{
    __shared__ float tile[32][33];
    const int z = blockIdx.z;
    in += (size_t)z * sin_;  oh += (size_t)z * sout;  ol += (size_t)z * sout;
    const int c0 = blockIdx.x * 32, r0 = blockIdx.y * 32;
    const int tr = threadIdx.x >> 3, tc = (threadIdx.x & 7) * 4;
    float4 v = *reinterpret_cast<const float4*>(in + (size_t)(r0 + tr) * W + c0 + tc);
    tile[tr][tc + 0] = v.x; tile[tr][tc + 1] = v.y;
    tile[tr][tc + 2] = v.z; tile[tr][tc + 3] = v.w;
    __syncthreads();
    ushort4 h4, l4;
    fsplit(tile[tc + 0][tr], h4.x, l4.x);
    fsplit(tile[tc + 1][tr], h4.y, l4.y);
    fsplit(tile[tc + 2][tr], h4.z, l4.z);
    fsplit(tile[tc + 3][tr], h4.w, l4.w);
    const size_t o = (size_t)(c0 + tr) * H + r0 + tc;
    *reinterpret_cast<ushort4*>(oh + o) = h4;
    *reinterpret_cast<ushort4*>(ol + o) = l4;
}

// ---- per-row causal sum of sp planes -> drec = 1/max(1,|sum|) --------------
__global__ __launch_bounds__(256) void denom_k(
    const us* __restrict__ sph, const us* __restrict__ spl,
    float* __restrict__ drec)
{
    const int r = blockIdx.x, b = blockIdx.y, t = threadIdx.x;
    const us* ph = sph + ((size_t)b * Ss + r) * Ss;
    const us* pl = spl + ((size_t)b * Ss + r) * Ss;
    const int jmax = ((r >> 7) + 1) << 7;     // written causal range (x128)
    float s = 0.f;
    for (int j4 = t; j4 * 4 < jmax; j4 += 256) {
        ushort4 h = *reinterpret_cast<const ushort4*>(ph + j4 * 4);
        ushort4 lo = *reinterpret_cast<const ushort4*>(pl + j4 * 4);
        s += (bf2f(h.x) + bf2f(lo.x)) + (bf2f(h.y) + bf2f(lo.y))
           + (bf2f(h.z) + bf2f(lo.z)) + (bf2f(h.w) + bf2f(lo.w));
    }
    __shared__ float rs[256];
    rs[t] = s;
    __syncthreads();
    for (int off = 128; off > 0; off >>= 1) {
        if (t < off) rs[t] += rs[t + off];
        __syncthreads();
    }
    if (t == 0) drec[(size_t)b * Ss + r] = 1.0f / fmaxf(1.0f, fabsf(rs[0]));
}

// ---- SwiGLU: out planes = split(a * silu(gate)) ----------------------------
__global__ __launch_bounds__(256) void swiglu_k(
    const float* __restrict__ m1, us* __restrict__ oh, us* __restrict__ ol)
{
    const size_t e = (size_t)blockIdx.x * 256 + threadIdx.x;   // B*S*D/4
    const size_t row = e / (Dd / 4);
    const int c4 = (int)(e % (Dd / 4));
    const float* base = m1 + row * (2 * Dd);
    float4 a = *reinterpret_cast<const float4*>(base + c4 * 4);
    float4 g = *reinterpret_cast<const float4*>(base + Dd + c4 * 4);
    float o0 = a.x * (g.x / (1.f + expf(-g.x)));
    float o1 = a.y * (g.y / (1.f + expf(-g.y)));
    float o2 = a.z * (g.z / (1.f + expf(-g.z)));
    float o3 = a.w * (g.w / (1.f + expf(-g.w)));
    ushort4 h4, l4;
    fsplit(o0, h4.x, l4.x); fsplit(o1, h4.y, l4.y);
    fsplit(o2, h4.z, l4.z); fsplit(o3, h4.w, l4.w);
    const size_t o = row * Dd + c4 * 4;
    *reinterpret_cast<ushort4*>(oh + o) = h4;
    *reinterpret_cast<ushort4*>(ol + o) = l4;
}

// ---- GroupNorm(1,D): per-batch mean/var over S*D ---------------------------
__global__ __launch_bounds__(256) void gn_part_k(
    const float* __restrict__ m2, float* __restrict__ part)
{
    const int b = blockIdx.y, blk = blockIdx.x;
    const float* p = m2 + (size_t)b * Ss * Dd + (size_t)blk * 8192;
    float s = 0.f, ss = 0.f;
    for (int t = threadIdx.x; t < 2048; t += 256) {
        float4 v = *reinterpret_cast<const float4*>(p + (size_t)t * 4);
        s  += (v.x + v.y) + (v.z + v.w);
        ss += v.x * v.x + v.y * v.y + v.z * v.z + v.w * v.w;
    }
    __shared__ float rs[256], rss[256];
    rs[threadIdx.x] = s; rss[threadIdx.x] = ss;
    __syncthreads();
    for (int off = 128; off > 0; off >>= 1) {
        if (threadIdx.x < off) {
            rs[threadIdx.x]  += rs[threadIdx.x + off];
            rss[threadIdx.x] += rss[threadIdx.x + off];
        }
        __syncthreads();
    }
    if (threadIdx.x == 0) {
        part[(b * 256 + blk) * 2]     = rs[0];
        part[(b * 256 + blk) * 2 + 1] = rss[0];
    }
}

__global__ __launch_bounds__(256) void gn_final_k(
    const float* __restrict__ part, float* __restrict__ stats)
{
    const int b = blockIdx.x, t = threadIdx.x;
    float s  = part[(b * 256 + t) * 2];
    float ss = part[(b * 256 + t) * 2 + 1];
    __shared__ float rs[256], rss[256];
    rs[t] = s; rss[t] = ss;
    __syncthreads();
    for (int off = 128; off > 0; off >>= 1) {
        if (t < off) { rs[t] += rs[t + off]; rss[t] += rss[t + off]; }
        __syncthreads();
    }
    if (t == 0) {
        const float inv_n = 1.0f / (float)((size_t)Ss * Dd);
        float mean = rs[0] * inv_n;
        float var  = fmaxf(rss[0] * inv_n - mean * mean, 0.0f);
        stats[b * 2]     = mean;
        stats[b * 2 + 1] = rsqrtf(var + 1e-5f);
    }
}

__global__ __launch_bounds__(256) void gn_apply_k(
    const float* __restrict__ m2, const float* __restrict__ h,
    const float* __restrict__ g, const float* __restrict__ bta,
    const float* __restrict__ stats, float* __restrict__ y,
    us* __restrict__ yh, us* __restrict__ yl)
{
    const size_t e = (size_t)blockIdx.x * 256 + threadIdx.x;   // B*S*D/4
    const int b  = (int)(e / ((size_t)Ss * Dd / 4));
    const int c4 = (int)(e % (Dd / 4));
    const float mean = stats[b * 2], istd = stats[b * 2 + 1];
    float4 m  = *reinterpret_cast<const float4*>(m2 + e * 4);
    float4 hh = *reinterpret_cast<const float4*>(h + e * 4);
    float4 g4 = *reinterpret_cast<const float4*>(g + c4 * 4);
    float4 b4 = *reinterpret_cast<const float4*>(bta + c4 * 4);
    float4 o;
    o.x = (m.x - mean) * istd * g4.x + b4.x + hh.x;
    o.y = (m.y - mean) * istd * g4.y + b4.y + hh.y;
    o.z = (m.z - mean) * istd * g4.z + b4.z + hh.z;
    o.w = (m.w - mean) * istd * g4.w + b4.w + hh.w;
    *reinterpret_cast<float4*>(y + e * 4) = o;
    ushort4 h4, l4;
    fsplit(o.x, h4.x, l4.x); fsplit(o.y, h4.y, l4.y);
    fsplit(o.z, h4.z, l4.z); fsplit(o.w, h4.w, l4.w);
    *reinterpret_cast<ushort4*>(yh + e * 4) = h4;
    *reinterpret_cast<ushort4*>(yl + e * 4) = l4;
}

// ---- LayerNorm over D; fp32 out (+ optional hi/lo planes for next layer) ---
template<bool SPLIT>
__global__ __launch_bounds__(256) void ln_k(
    const float* __restrict__ f2, const float* __restrict__ y,
    const float* __restrict__ g, const float* __restrict__ bta,
    float* __restrict__ out, us* __restrict__ oh, us* __restrict__ ol)
{
    const int row = blockIdx.x;          // 0 .. B*S-1
    const int t = threadIdx.x;           // 256 threads, 4 elems each
    float4 fv = *reinterpret_cast<const float4*>(f2 + (size_t)row * Dd + t * 4);
    float4 yv = *reinterpret_cast<const float4*>(y  + (size_t)row * Dd + t * 4);
    const float v0 = fv.x + yv.x, v1 = fv.y + yv.y;
    const float v2 = fv.z + yv.z, v3 = fv.w + yv.w;
    float s  = (v0 + v1) + (v2 + v3);
    float ss = v0 * v0 + v1 * v1 + v2 * v2 + v3 * v3;
    __shared__ float rs[256], rss[256];
    rs[t] = s; rss[t] = ss;
    __syncthreads();
    for (int off = 128; off > 0; off >>= 1) {
        if (t < off) { rs[t] += rs[t + off]; rss[t] += rss[t + off]; }
        __syncthreads();
    }
    const float mean = rs[0] * (1.0f / Dd);
    const float var  = fmaxf(rss[0] * (1.0f / Dd) - mean * mean, 0.0f);
    const float istd = rsqrtf(var + 1e-5f);
    float4 g4 = *reinterpret_cast<const float4*>(g + t * 4);
    float4 b4 = *reinterpret_cast<const float4*>(bta + t * 4);
    float4 o;
    o.x = (v0 - mean) * istd * g4.x + b4.x;
    o.y = (v1 - mean) * istd * g4.y + b4.y;
    o.z = (v2 - mean) * istd * g4.z + b4.z;
    o.w = (v3 - mean) * istd * g4.w + b4.w;
    *reinterpret_cast<float4*>(out + (size_t)row * Dd + t * 4) = o;
    if (SPLIT) {
        ushort4 h4, l4;
        fsplit(o.x, h4.x, l4.x); fsplit(o.y, h4.y, l4.y);
        fsplit(o.z, h4.z, l4.z); fsplit(o.w, h4.w, l4.w);
        const size_t e = (size_t)row * Dd + t * 4;
        *reinterpret_cast<ushort4*>(oh + e) = h4;
        *reinterpret_cast<ushort4*>(ol + e) = l4;
    }
}

extern "C" void kernel_launch(void* const* d_in, const int* in_sizes, int n_in,
                              void* d_out, int out_size, void* d_ws, size_t ws_size,
                              hipStream_t stream)
{
    const float* x    = (const float*)d_in[0];
    const float* Wkqv = (const float*)d_in[1];
    const float* Wm1  = (const float*)d_in[2];
    const float* bm1  = (const float*)d_in[3];
    const float* Wm2  = (const float*)d_in[4];
    const float* bm2  = (const float*)d_in[5];
    const float* gng  = (const float*)d_in[6];
    const float* gnb  = (const float*)d_in[7];
    const float* Wf1  = (const float*)d_in[8];
    const float* bf1  = (const float*)d_in[9];
    const float* Wf2  = (const float*)d_in[10];
    const float* bf2  = (const float*)d_in[11];
    const float* lng  = (const float*)d_in[12];
    const float* lnb  = (const float*)d_in[13];

    // 16 MiB slots S0..S11, lifetime-colored; peak exactly 192 MiB.
    char* wsb = (char*)d_ws;
    const size_t MiB = 1024 * 1024;
    auto SL = [&](int i) { return wsb + (size_t)i * 16 * MiB; };

    float* hbuf   = (float*)SL(0);
    us* h_hi      = (us*)SL(2);
    us* h_lo      = (us*)SL(3);
    us* qk_hi     = (us*)SL(4);                 // [8192][2048] = 32 MiB
    us* qk_lo     = (us*)SL(6);
    float* vbuf   = (float*)SL(8);              // 32 MiB
    us* WtA_hi    = (us*)SL(10);                // [3072][1024] = 6 MiB
    us* WtA_lo    = (us*)(SL(10) + 6 * MiB);
    us* vT_hi     = (us*)SL(2);                 // [4][1024][2048] = 16 MiB
    us* vT_lo     = (us*)SL(3);
    us* sp_hi     = (us*)SL(8);                 // [4][2048][2048] = 32 MiB
    us* sp_lo     = (us*)SL(10);
    float* drec   = (float*)SL(4);              // [4][2048] = 32 KiB
    us* ret_hi    = (us*)SL(6);
    us* ret_lo    = (us*)SL(7);
    us* Wt1_hi    = (us*)SL(2);                 // [2048][1024] = 4 MiB
    us* Wt1_lo    = (us*)(SL(2) + 4 * MiB);
    float* m1     = (float*)SL(8);              // [8192][2048] = 64 MiB
    us* sw_hi     = (us*)SL(4);
    us* sw_lo     = (us*)SL(5);
    us* Wt2_hi    = (us*)SL(2);                 // [1024][1024] = 2 MiB
    us* Wt2_lo    = (us*)(SL(2) + 2 * MiB);
    float* m2     = (float*)SL(10);             // 32 MiB
    float* part   = (float*)SL(2);
    float* stats  = (float*)(SL(2) + 1 * MiB);
    float* ybuf   = (float*)SL(8);              // 32 MiB
    us* y_hi      = (us*)SL(4);
    us* y_lo      = (us*)SL(5);
    us* Wtf1_hi   = (us*)SL(6);                 // [2048][1024] = 4 MiB
    us* Wtf1_lo   = (us*)(SL(6) + 4 * MiB);
    us* f1_hi     = (us*)SL(10);                // [8192][2048] = 32 MiB
    us* f1_lo     = (us*)SL(2);
    us* Wtf2_hi   = (us*)SL(6);                 // [1024][2048] = 4 MiB
    us* Wtf2_lo   = (us*)(SL(6) + 4 * MiB);
    float* f2     = (float*)SL(4);              // 32 MiB

    for (int l = 0; l < Ll; ++l) {
        const float* h = (l == 0) ? x : hbuf;
        if (l == 0)
            split_k<<<8192, 256, 0, stream>>>(x, h_hi, h_lo);

        // ---- QKV ----------------------------------------------------------
        tsplit_k<<<dim3(3 * Dd / 32, Dd / 32, 1), 256, 0, stream>>>(
            Wkqv + (size_t)l * Dd * 3 * Dd, 0, WtA_hi, WtA_lo, 0, Dd, 3 * Dd);
        // cols 0:2048 -> [k | q] planes  (256x256 kernel, grid 8x32, 1 round)
        gemm3w<1, false, 0><<<dim3(8, 32), 512, 0, stream>>>(
            h_hi, h_lo, Dd, WtA_hi, WtA_lo, Dd, nullptr,
            nullptr, qk_hi, qk_lo, 2 * Dd, Dd);
        // cols 2048:3072 -> v fp32
        gemm3<0, false, 0, false, false, false><<<dim3(8, 64, 1), 256, 0, stream>>>(
            h_hi, h_lo, Dd, 0,
            WtA_hi + (size_t)2 * Dd * Dd, WtA_lo + (size_t)2 * Dd * Dd, Dd, 0,
            nullptr, vbuf, nullptr, nullptr, Dd, 0, drec, Dd);
        tsplit_k<<<dim3(Dd / 32, Ss / 32, Bb), 256, 0, stream>>>(
            vbuf, (long)Ss * Dd, vT_hi, vT_lo, (long)Dd * Ss, Ss, Dd);

        // ---- retention ----------------------------------------------------
        // scores = tril(q k^T)/(32(1+sqrt(i))), written as scaled hi/lo planes
        gemm3<1, false, 0, true, false, false><<<dim3(16, 16, Bb), 256, 0, stream>>>(
            qk_hi + Dd, qk_lo + Dd, 2 * Dd, (long)Ss * 2 * Dd,    // q
            qk_hi,      qk_lo,      2 * Dd, (long)Ss * 2 * Dd,    // k
            nullptr, nullptr, sp_hi, sp_lo, Ss, (long)Ss * Ss, drec, Dd);
        denom_k<<<dim3(Ss, Bb), 256, 0, stream>>>(sp_hi, sp_lo, drec);
        // ret = (scores/denom) @ v  -> split planes
        gemm3<1, false, 0, false, true, true><<<dim3(8, 16, Bb), 256, 0, stream>>>(
            sp_hi, sp_lo, Ss, (long)Ss * Ss,
            vT_hi, vT_lo, Ss, (long)Dd * Ss,
            nullptr, nullptr, ret_hi, ret_lo, Dd, (long)Ss * Dd, drec, Ss);

        // ---- SwiGLU MLP ---------------------------------------------------
        tsplit_k<<<dim3(2 * Dd / 32, Dd / 32, 1), 256, 0, stream>>>(
            Wm1 + (size_t)l * Dd * 2 * Dd, 0, Wt1_hi, Wt1_lo, 0, Dd, 2 * Dd);
        gemm3w<0, true, 0><<<dim3(8, 32), 512, 0, stream>>>(
            ret_hi, ret_lo, Dd, Wt1_hi, Wt1_lo, Dd,
            bm1 + (size_t)l * 2 * Dd, m1, nullptr, nullptr, 2 * Dd, Dd);
        swiglu_k<<<8192, 256, 0, stream>>>(m1, sw_hi, sw_lo);
        tsplit_k<<<dim3(Dd / 32, Dd / 32, 1), 256, 0, stream>>>(
            Wm2 + (size_t)l * Dd * Dd, 0, Wt2_hi, Wt2_lo, 0, Dd, Dd);
        gemm3<0, true, 0, false, false, false><<<dim3(8, 64, 1), 256, 0, stream>>>(
            sw_hi, sw_lo, Dd, 0, Wt2_hi, Wt2_lo, Dd, 0,
            bm2 + (size_t)l * Dd, m2, nullptr, nullptr, Dd, 0, drec, Dd);

        // ---- GroupNorm + residual ----------------------------------------
        gn_part_k<<<dim3(256, Bb), 256, 0, stream>>>(m2, part);
        gn_final_k<<<Bb, 256, 0, stream>>>(part, stats);
        gn_apply_k<<<8192, 256, 0, stream>>>(
            m2, h, gng + (size_t)l * Dd, gnb + (size_t)l * Dd, stats,
            ybuf, y_hi, y_lo);

        // ---- FFN ----------------------------------------------------------
        tsplit_k<<<dim3(2 * Dd / 32, Dd / 32, 1), 256, 0, stream>>>(
            Wf1 + (size_t)l * Dd * 2 * Dd, 0, Wtf1_hi, Wtf1_lo, 0, Dd, 2 * Dd);
        gemm3w<1, true, 1><<<dim3(8, 32), 512, 0, stream>>>(
            y_hi, y_lo, Dd, Wtf1_hi, Wtf1_lo, Dd,
            bf1 + (size_t)l * 2 * Dd,
            nullptr, f1_hi, f1_lo, 2 * Dd, Dd);               // GELU fused
        tsplit_k<<<dim3(Dd / 32, 2 * Dd / 32, 1), 256, 0, stream>>>(
            Wf2 + (size_t)l * 2 * Dd * Dd, 0, Wtf2_hi, Wtf2_lo, 0, 2 * Dd, Dd);
        gemm3<0, true, 0, false, false, false><<<dim3(8, 64, 1), 256, 0, stream>>>(
            f1_hi, f1_lo, 2 * Dd, 0, Wtf2_hi, Wtf2_lo, 2 * Dd, 0,
            bf2 + (size_t)l * Dd, f2, nullptr, nullptr, Dd, 0, drec, 2 * Dd);

        // ---- LayerNorm ----------------------------------------------------
        if (l == Ll - 1)
            ln_k<false><<<BSm, 256, 0, stream>>>(
                f2, ybuf, lng + (size_t)l * Dd, lnb + (size_t)l * Dd,
                (float*)d_out, nullptr, nullptr);
        else
            ln_k<true><<<BSm, 256, 0, stream>>>(
                f2, ybuf, lng + (size_t)l * Dd, lnb + (size_t)l * Dd,
                hbuf, h_hi, h_lo);
    }
}

// Round 9
// 3257.616 us; speedup vs baseline: 1.0548x; 1.0548x over previous
//
#include <hip/hip_runtime.h>

// bf16x3 MFMA: every GEMM runs as hi*hi + hi*lo + lo*hi on
// __builtin_amdgcn_mfma_f32_16x16x32_bf16 (fp32 accumulate).
// Round-7 structure (best: simple 2-phase, one __syncthreads per K-tile,
// stage(kt+1) before compute(kt), proven staging pattern) + XCD row-band
// swizzle (T1) on the z==1 GEMMs: blocks sharing an A-panel co-locate on
// one XCD's L2, cutting cross-XCD L2 fill traffic (FETCH_SIZE 135MB -> ~95MB
// predicted) and fill latency.
//   gemm3  : 128x128 tile, 256 thr (4 waves 2x2), 64 KiB LDS, 2 blocks/CU.
//   gemm3w : 256x256 tile, 512 thr (8 waves 2x4), 128 KiB LDS, 1 block/CU.

constexpr int Bb = 4, Ss = 2048, Dd = 1024, Ll = 4;
constexpr int BSm = Bb * Ss;          // 8192 rows flattened

typedef short bf16x8 __attribute__((ext_vector_type(8)));
typedef float f32x4  __attribute__((ext_vector_type(4)));
typedef unsigned short us;

__device__ __forceinline__ us bf16_rn(float x) {
    unsigned int u = __float_as_uint(x);
    u += 0x7FFFu + ((u >> 16) & 1u);
    return (us)(u >> 16);
}
__device__ __forceinline__ float bf2f(us h) {
    return __uint_as_float(((unsigned int)h) << 16);
}
__device__ __forceinline__ void fsplit(float v, us& h, us& l) {
    h = bf16_rn(v);
    l = bf16_rn(v - bf2f(h));      // exact subtraction (Sterbenz range)
}

#define GLL(g, l) __builtin_amdgcn_global_load_lds( \
    (const __attribute__((address_space(1))) void*)(g), \
    (__attribute__((address_space(3))) void*)(l), 16, 0, 0)

#define MFMA16(a, b, c) __builtin_amdgcn_mfma_f32_16x16x32_bf16(a, b, c, 0, 0, 0)

// XCD row-band swizzle: bijective remap of (gx,gy) so that linear-bid%8
// (assumed XCD assignment) selects a contiguous row-band.  All col-blocks
// of a row-band then share one XCD's L2 for their A-panels.
// Requires gridDim.y % 8 == 0 (all SWZ call sites: ny = 32 or 64).
__device__ __forceinline__ void xcd_swizzle(int& gx, int& gy) {
    const int nx = gridDim.x, ny = gridDim.y;
    const int bid = gy * nx + gx;
    const int xcd = bid & 7, idx = bid >> 3;
    gy = xcd * (ny >> 3) + idx / nx;
    gx = idx % nx;
}

// ---------------------------------------------------------------------------
// gemm3: 128x128, BK=32, 256 thr (4 waves 2x2).  Round-7 kernel + SWZ.
// A planes [M][K] row-major; B planes [N][K] row-major (W^T).
// ---------------------------------------------------------------------------
template<int OUT, bool HAS_BIAS, int ACT, bool CAUSAL, bool CK, bool ROWSCALE, bool SWZ>
__global__ __launch_bounds__(256, 2) void gemm3(
    const us* __restrict__ Ahg, const us* __restrict__ Alg, int lda, long sA,
    const us* __restrict__ Bhg, const us* __restrict__ Blg, int ldb, long sB,
    const float* __restrict__ bias,
    float* __restrict__ Cf, us* __restrict__ Ch, us* __restrict__ Cl,
    int ldc, long sC,
    const float* __restrict__ drec, int K)
{
    __shared__ __align__(16) char lds[2 * 32768];   // 64 KiB

    int gx = blockIdx.x, gy = blockIdx.y;
    if (SWZ) xcd_swizzle(gx, gy);
    if (CAUSAL && gx > gy) return;                   // above diagonal: dead
    const int t = threadIdx.x, z = blockIdx.z;
    const int row0 = gy * 128, col0 = gx * 128;
    Ahg += (size_t)z * sA;  Alg += (size_t)z * sA;
    Bhg += (size_t)z * sB;  Blg += (size_t)z * sB;

    const int srow = t >> 2;
    const int scg  = ((t & 3) ^ ((t >> 3) & 3)) * 8;
    const us* pAh = Ahg + (size_t)(row0 + srow) * lda + scg;
    const us* pAl = Alg + (size_t)(row0 + srow) * lda + scg;
    const us* pBh = Bhg + (size_t)(col0 + srow) * ldb + scg;
    const us* pBl = Blg + (size_t)(col0 + srow) * ldb + scg;
    const size_t a64 = (size_t)64 * lda, b64 = (size_t)64 * ldb;
    const int wb = (t >> 6) * 1024;       // wave-uniform byte base per round

    auto stage = [&](int kt) {
        const int k0 = kt * 32;
        char* base = lds + (kt & 1) * 32768 + wb;
        GLL(pAh + k0,       base + 0 * 8192);
        GLL(pAh + k0 + a64, base + 0 * 8192 + 4096);
        GLL(pAl + k0,       base + 1 * 8192);
        GLL(pAl + k0 + a64, base + 1 * 8192 + 4096);
        GLL(pBh + k0,       base + 2 * 8192);
        GLL(pBh + k0 + b64, base + 2 * 8192 + 4096);
        GLL(pBl + k0,       base + 3 * 8192);
        GLL(pBl + k0 + b64, base + 3 * 8192 + 4096);
    };

    const int ln = t & 63, lr = ln & 15, q = ln >> 4;
    const int w  = t >> 6, wm = w >> 1, wn = w & 1;
    const int xq = (q ^ ((lr >> 1) & 3)) * 16;   // swizzled 16B slot offset
    int offA[4], offB[4];
    #pragma unroll
    for (int m = 0; m < 4; ++m) offA[m] = (wm * 64 + m * 16 + lr) * 64 + xq;
    #pragma unroll
    for (int n = 0; n < 4; ++n) offB[n] = (wn * 64 + n * 16 + lr) * 64 + xq;

    f32x4 acc[4][4] = {};

    int Keff = K;
    if (CK) { int ke = row0 + 128; Keff = ke < K ? ke : K; }
    const int NT = Keff >> 5;             // >= 4 always

    stage(0);
    for (int kt = 0; kt < NT; ++kt) {
        __syncthreads();                  // stage(kt) landed; prev reads done
        if (kt + 1 < NT) stage(kt + 1);   // other buffer; hides under compute
        const char* base = lds + (kt & 1) * 32768;
        bf16x8 ah[4], al8[4], bh[4], bl8[4];
        #pragma unroll
        for (int m = 0; m < 4; ++m) {
            ah[m]  = *reinterpret_cast<const bf16x8*>(base + 0 * 8192 + offA[m]);
            al8[m] = *reinterpret_cast<const bf16x8*>(base + 1 * 8192 + offA[m]);
        }
        #pragma unroll
        for (int n = 0; n < 4; ++n) {
            bh[n]  = *reinterpret_cast<const bf16x8*>(base + 2 * 8192 + offB[n]);
            bl8[n] = *reinterpret_cast<const bf16x8*>(base + 3 * 8192 + offB[n]);
        }
        #pragma unroll
        for (int n = 0; n < 4; ++n) {
            #pragma unroll
            for (int m = 0; m < 4; ++m) acc[m][n] = MFMA16(ah[m],  bh[n],  acc[m][n]);
            #pragma unroll
            for (int m = 0; m < 4; ++m) acc[m][n] = MFMA16(ah[m],  bl8[n], acc[m][n]);
            #pragma unroll
            for (int m = 0; m < 4; ++m) acc[m][n] = MFMA16(al8[m], bh[n],  acc[m][n]);
        }
    }

    const float* dz = drec + (size_t)z * Ss;   // only read when ROWSCALE
    #pragma unroll
    for (int n = 0; n < 4; ++n) {
        const int col = col0 + wn * 64 + n * 16 + lr;
        const float bv = HAS_BIAS ? bias[col] : 0.0f;
        #pragma unroll
        for (int m = 0; m < 4; ++m) {
            #pragma unroll
            for (int j = 0; j < 4; ++j) {
                const int row = row0 + wm * 64 + m * 16 + 4 * q + j;
                float v = acc[m][n][j] + bv;
                if (ACT == 1)
                    v = 0.5f * v * (1.0f + erff(v * 0.70710678118f));
                if (CAUSAL)
                    v = (col <= row)
                        ? v * (1.0f / (32.0f * (1.0f + sqrtf((float)row))))
                        : 0.0f;
                if (ROWSCALE) v *= dz[row];
                const size_t idx = (size_t)z * sC + (size_t)row * ldc + col;
                if (OUT == 0) {
                    Cf[idx] = v;
                } else {
                    us h_, l_;
                    fsplit(v, h_, l_);
                    Ch[idx] = h_;
                    Cl[idx] = l_;
                }
            }
        }
    }
}

// ---------------------------------------------------------------------------
// gemm3w: 256x256, BK=32, 512 thr = 8 waves (2m x 4n), wave tile 128x64.
// Round-7 kernel + SWZ.  LDS per buffer: Ah|Al|Bh|Bl 16K each; 2 buf = 128K.
// Panel byte addr of (row R, group g): (R&127)*64 + g*16 + (R>>7)*8192.
// ---------------------------------------------------------------------------
template<int OUT, bool HAS_BIAS, int ACT>
__global__ __launch_bounds__(512, 2) void gemm3w(
    const us* __restrict__ Ahg, const us* __restrict__ Alg, int lda,
    const us* __restrict__ Bhg, const us* __restrict__ Blg, int ldb,
    const float* __restrict__ bias,
    float* __restrict__ Cf, us* __restrict__ Ch, us* __restrict__ Cl,
    int ldc, int K)
{
    __shared__ __align__(16) char lds[2 * 65536];   // 128 KiB

    int gx = blockIdx.x, gy = blockIdx.y;
    xcd_swizzle(gx, gy);
    const int t = threadIdx.x;
    const int row0 = gy * 256, col0 = gx * 256;

    const int srow = t >> 2;                        // 0..127
    const int scg  = ((t & 3) ^ ((t >> 3) & 3)) * 8;
    const us* pAh = Ahg + (size_t)(row0 + srow) * lda + scg;
    const us* pAl = Alg + (size_t)(row0 + srow) * lda + scg;
    const us* pBh = Bhg + (size_t)(col0 + srow) * ldb + scg;
    const us* pBl = Blg + (size_t)(col0 + srow) * ldb + scg;
    const size_t a128 = (size_t)128 * lda, b128 = (size_t)128 * ldb;
    const int wb = (t >> 6) * 1024;       // wave-uniform byte base per round

    auto stage = [&](int kt) {
        const int k0 = kt * 32;
        char* base = lds + (kt & 1) * 65536 + wb;
        GLL(pAh + k0,        base + 0 * 16384);
        GLL(pAh + k0 + a128, base + 0 * 16384 + 8192);
        GLL(pAl + k0,        base + 1 * 16384);
        GLL(pAl + k0 + a128, base + 1 * 16384 + 8192);
        GLL(pBh + k0,        base + 2 * 16384);
        GLL(pBh + k0 + b128, base + 2 * 16384 + 8192);
        GLL(pBl + k0,        base + 3 * 16384);
        GLL(pBl + k0 + b128, base + 3 * 16384 + 8192);
    };

    const int ln = t & 63, lr = ln & 15, q = ln >> 4;
    const int w  = t >> 6, wm = w >> 2, wn = w & 3;   // 2m x 4n
    const int xq = (q ^ ((lr >> 1) & 3)) * 16;
    int offA[8], offB[4];
    #pragma unroll
    for (int m = 0; m < 8; ++m)          // A rows: wm*128 + m*16 + lr
        offA[m] = (m * 16 + lr) * 64 + xq + wm * 8192;
    #pragma unroll
    for (int n = 0; n < 4; ++n) {        // B rows: wn*64 + n*16 + lr
        const int R = wn * 64 + n * 16 + lr;
        offB[n] = (R & 127) * 64 + xq + (R >> 7) * 8192;
    }

    f32x4 acc[8][4] = {};
    const int NT = K >> 5;

    stage(0);
    for (int kt = 0; kt < NT; ++kt) {
        __syncthreads();                  // stage(kt) landed; prev reads done
        if (kt + 1 < NT) stage(kt + 1);
        const char* base = lds + (kt & 1) * 65536;
        bf16x8 ah[8], al8[8];
        #pragma unroll
        for (int m = 0; m < 8; ++m) {
            ah[m]  = *reinterpret_cast<const bf16x8*>(base + 0 * 16384 + offA[m]);
            al8[m] = *reinterpret_cast<const bf16x8*>(base + 1 * 16384 + offA[m]);
        }
        #pragma unroll
        for (int n = 0; n < 4; ++n) {
            bf16x8 bh  = *reinterpret_cast<const bf16x8*>(base + 2 * 16384 + offB[n]);
            bf16x8 bl8 = *reinterpret_cast<const bf16x8*>(base + 3 * 16384 + offB[n]);
            #pragma unroll
            for (int m = 0; m < 8; ++m) acc[m][n] = MFMA16(ah[m],  bh,  acc[m][n]);
            #pragma unroll
            for (int m = 0; m < 8; ++m) acc[m][n] = MFMA16(ah[m],  bl8, acc[m][n]);
            #pragma unroll
            for (int m = 0; m < 8; ++m) acc[m][n] = MFMA16(al8[m], bh,  acc[m][n]);
        }
    }

    #pragma unroll
    for (int n = 0; n < 4; ++n) {
        const int col = col0 + wn * 64 + n * 16 + lr;
        const float bv = HAS_BIAS ? bias[col] : 0.0f;
        #pragma unroll
        for (int m = 0; m < 8; ++m) {
            #pragma unroll
            for (int j = 0; j < 4; ++j) {
                const int row = row0 + wm * 128 + m * 16 + 4 * q + j;
                float v = acc[m][n][j] + bv;
                if (ACT == 1)
                    v = 0.5f * v * (1.0f + erff(v * 0.70710678118f));
                const size_t idx = (size_t)row * ldc + col;
                if (OUT == 0) {
                    Cf[idx] = v;
                } else {
                    us h_, l_;
                    fsplit(v, h_, l_);
                    Ch[idx] = h_;
                    Cl[idx] = l_;
                }
            }
        }
    }
}

// ---- elementwise fp32 -> hi/lo split (layer-0 x only) ----------------------
__global__ __launch_bounds__(256) void split_k(
    const float* __restrict__ in, us* __restrict__ oh, us* __restrict__ ol)
{
    const size_t e = (size_t)blockIdx.x * 256 + threadIdx.x;
    float4 v = *reinterpret_cast<const float4*>(in + e * 4);
    ushort4 h4, l4;
    fsplit(v.x, h4.x, l4.x); fsplit(v.y, h4.y, l4.y);
    fsplit(v.z, h4.z, l4.z); fsplit(v.w, h4.w, l4.w);
    *reinterpret_cast<ushort4*>(oh + e * 4) = h4;
    *reinterpret_cast<ushort4*>(ol + e * 4) = l4;
}

// ---- transpose + split: in fp32 [H][W] -> out [W][H] hi/lo bf16 ------------
__global__ __launch_bounds__(256) void tsplit_k(
    const float* __restrict__ in, long sin_,
    us* __restrict__ oh, us* __restrict__ ol, long sout, int H, int W)
{
    __shared__ float tile[32][33];
    const int z = blockIdx.z;
    in += (size_t)z * sin_;  oh += (size_t)z * sout;  ol += (size_t)z * sout;
    const int c0 = blockIdx.x * 32, r0 = blockIdx.y * 32;
    const int tr = threadIdx.x >> 3, tc = (threadIdx.x & 7) * 4;
    float4 v = *reinterpret_cast<const float4*>(in + (size_t)(r0 + tr) * W + c0 + tc);
    tile[tr][tc + 0] = v.x; tile[tr][tc + 1] = v.y;
    tile[tr][tc + 2] = v.z; tile[tr][tc + 3] = v.w;
    __syncthreads();
    ushort4 h4, l4;
    fsplit(tile[tc + 0][tr], h4.x, l4.x);
    fsplit(tile[tc + 1][tr], h4.y, l4.y);
    fsplit(tile[tc + 2][tr], h4.z, l4.z);
    fsplit(tile[tc + 3][tr], h4.w, l4.w);
    const size_t o = (size_t)(c0 + tr) * H + r0 + tc;
    *reinterpret_cast<ushort4*>(oh + o) = h4;
    *reinterpret_cast<ushort4*>(ol + o) = l4;
}

// ---- per-row causal sum of sp planes -> drec = 1/max(1,|sum|) --------------
__global__ __launch_bounds__(256) void denom_k(
    const us* __restrict__ sph, const us* __restrict__ spl,
    float* __restrict__ drec)
{
    const int r = blockIdx.x, b = blockIdx.y, t = threadIdx.x;
    const us* ph = sph + ((size_t)b * Ss + r) * Ss;
    const us* pl = spl + ((size_t)b * Ss + r) * Ss;
    const int jmax = ((r >> 7) + 1) << 7;     // written causal range (x128)
    float s = 0.f;
    for (int j4 = t; j4 * 4 < jmax; j4 += 256) {
        ushort4 h = *reinterpret_cast<const ushort4*>(ph + j4 * 4);
        ushort4 lo = *reinterpret_cast<const ushort4*>(pl + j4 * 4);
        s += (bf2f(h.x) + bf2f(lo.x)) + (bf2f(h.y) + bf2f(lo.y))
           + (bf2f(h.z) + bf2f(lo.z)) + (bf2f(h.w) + bf2f(lo.w));
    }
    __shared__ float rs[256];
    rs[t] = s;
    __syncthreads();
    for (int off = 128; off > 0; off >>= 1) {
        if (t < off) rs[t] += rs[t + off];
        __syncthreads();
    }
    if (t == 0) drec[(size_t)b * Ss + r] = 1.0f / fmaxf(1.0f, fabsf(rs[0]));
}

// ---- SwiGLU: out planes = split(a * silu(gate)) ----------------------------
__global__ __launch_bounds__(256) void swiglu_k(
    const float* __restrict__ m1, us* __restrict__ oh, us* __restrict__ ol)
{
    const size_t e = (size_t)blockIdx.x * 256 + threadIdx.x;   // B*S*D/4
    const size_t row = e / (Dd / 4);
    const int c4 = (int)(e % (Dd / 4));
    const float* base = m1 + row * (2 * Dd);
    float4 a = *reinterpret_cast<const float4*>(base + c4 * 4);
    float4 g = *reinterpret_cast<const float4*>(base + Dd + c4 * 4);
    float o0 = a.x * (g.x / (1.f + expf(-g.x)));
    float o1 = a.y * (g.y / (1.f + expf(-g.y)));
    float o2 = a.z * (g.z / (1.f + expf(-g.z)));
    float o3 = a.w * (g.w / (1.f + expf(-g.w)));
    ushort4 h4, l4;
    fsplit(o0, h4.x, l4.x); fsplit(o1, h4.y, l4.y);
    fsplit(o2, h4.z, l4.z); fsplit(o3, h4.w, l4.w);
    const size_t o = row * Dd + c4 * 4;
    *reinterpret_cast<ushort4*>(oh + o) = h4;
    *reinterpret_cast<ushort4*>(ol + o) = l4;
}

// ---- GroupNorm(1,D): per-batch mean/var over S*D ---------------------------
__global__ __launch_bounds__(256) void gn_part_k(
    const float* __restrict__ m2, float* __restrict__ part)
{
    const int b = blockIdx.y, blk = blockIdx.x;
    const float* p = m2 + (size_t)b * Ss * Dd + (size_t)blk * 8192;
    float s = 0.f, ss = 0.f;
    for (int t = threadIdx.x; t < 2048; t += 256) {
        float4 v = *reinterpret_cast<const float4*>(p + (size_t)t * 4);
        s  += (v.x + v.y) + (v.z + v.w);
        ss += v.x * v.x + v.y * v.y + v.z * v.z + v.w * v.w;
    }
    __shared__ float rs[256], rss[256];
    rs[threadIdx.x] = s; rss[threadIdx.x] = ss;
    __syncthreads();
    for (int off = 128; off > 0; off >>= 1) {
        if (threadIdx.x < off) {
            rs[threadIdx.x]  += rs[threadIdx.x + off];
            rss[threadIdx.x] += rss[threadIdx.x + off];
        }
        __syncthreads();
    }
    if (threadIdx.x == 0) {
        part[(b * 256 + blk) * 2]     = rs[0];
        part[(b * 256 + blk) * 2 + 1] = rss[0];
    }
}

__global__ __launch_bounds__(256) void gn_final_k(
    const float* __restrict__ part, float* __restrict__ stats)
{
    const int b = blockIdx.x, t = threadIdx.x;
    float s  = part[(b * 256 + t) * 2];
    float ss = part[(b * 256 + t) * 2 + 1];
    __shared__ float rs[256], rss[256];
    rs[t] = s; rss[t] = ss;
    __syncthreads();
    for (int off = 128; off > 0; off >>= 1) {
        if (t < off) { rs[t] += rs[t + off]; rss[t] += rss[t + off]; }
        __syncthreads();
    }
    if (t == 0) {
        const float inv_n = 1.0f / (float)((size_t)Ss * Dd);
        float mean = rs[0] * inv_n;
        float var  = fmaxf(rss[0] * inv_n - mean * mean, 0.0f);
        stats[b * 2]     = mean;
        stats[b * 2 + 1] = rsqrtf(var + 1e-5f);
    }
}

__global__ __launch_bounds__(256) void gn_apply_k(
    const float* __restrict__ m2, const float* __restrict__ h,
    const float* __restrict__ g, const float* __restrict__ bta,
    const float* __restrict__ stats, float* __restrict__ y,
    us* __restrict__ yh, us* __restrict__ yl)
{
    const size_t e = (size_t)blockIdx.x * 256 + threadIdx.x;   // B*S*D/4
    const int b  = (int)(e / ((size_t)Ss * Dd / 4));
    const int c4 = (int)(e % (Dd / 4));
    const float mean = stats[b * 2], istd = stats[b * 2 + 1];
    float4 m  = *reinterpret_cast<const float4*>(m2 + e * 4);
    float4 hh = *reinterpret_cast<const float4*>(h + e * 4);
    float4 g4 = *reinterpret_cast<const float4*>(g + c4 * 4);
    float4 b4 = *reinterpret_cast<const float4*>(bta + c4 * 4);
    float4 o;
    o.x = (m.x - mean) * istd * g4.x + b4.x + hh.x;
    o.y = (m.y - mean) * istd * g4.y + b4.y + hh.y;
    o.z = (m.z - mean) * istd * g4.z + b4.z + hh.z;
    o.w = (m.w - mean) * istd * g4.w + b4.w + hh.w;
    *reinterpret_cast<float4*>(y + e * 4) = o;
    ushort4 h4, l4;
    fsplit(o.x, h4.x, l4.x); fsplit(o.y, h4.y, l4.y);
    fsplit(o.z, h4.z, l4.z); fsplit(o.w, h4.w, l4.w);
    *reinterpret_cast<ushort4*>(yh + e * 4) = h4;
    *reinterpret_cast<ushort4*>(yl + e * 4) = l4;
}

// ---- LayerNorm over D; fp32 out (+ optional hi/lo planes for next layer) ---
template<bool SPLIT>
__global__ __launch_bounds__(256) void ln_k(
    const float* __restrict__ f2, const float* __restrict__ y,
    const float* __restrict__ g, const float* __restrict__ bta,
    float* __restrict__ out, us* __restrict__ oh, us* __restrict__ ol)
{
    const int row = blockIdx.x;          // 0 .. B*S-1
    const int t = threadIdx.x;           // 256 threads, 4 elems each
    float4 fv = *reinterpret_cast<const float4*>(f2 + (size_t)row * Dd + t * 4);
    float4 yv = *reinterpret_cast<const float4*>(y  + (size_t)row * Dd + t * 4);
    const float v0 = fv.x + yv.x, v1 = fv.y + yv.y;
    const float v2 = fv.z + yv.z, v3 = fv.w + yv.w;
    float s  = (v0 + v1) + (v2 + v3);
    float ss = v0 * v0 + v1 * v1 + v2 * v2 + v3 * v3;
    __shared__ float rs[256], rss[256];
    rs[t] = s; rss[t] = ss;
    __syncthreads();
    for (int off = 128; off > 0; off >>= 1) {
        if (t < off) { rs[t] += rs[t + off]; rss[t] += rss[t + off]; }
        __syncthreads();
    }
    const float mean = rs[0] * (1.0f / Dd);
    const float var  = fmaxf(rss[0] * (1.0f / Dd) - mean * mean, 0.0f);
    const float istd = rsqrtf(var + 1e-5f);
    float4 g4 = *reinterpret_cast<const float4*>(g + t * 4);
    float4 b4 = *reinterpret_cast<const float4*>(bta + t * 4);
    float4 o;
    o.x = (v0 - mean) * istd * g4.x + b4.x;
    o.y = (v1 - mean) * istd * g4.y + b4.y;
    o.z = (v2 - mean) * istd * g4.z + b4.z;
    o.w = (v3 - mean) * istd * g4.w + b4.w;
    *reinterpret_cast<float4*>(out + (size_t)row * Dd + t * 4) = o;
    if (SPLIT) {
        ushort4 h4, l4;
        fsplit(o.x, h4.x, l4.x); fsplit(o.y, h4.y, l4.y);
        fsplit(o.z, h4.z, l4.z); fsplit(o.w, h4.w, l4.w);
        const size_t e = (size_t)row * Dd + t * 4;
        *reinterpret_cast<ushort4*>(oh + e) = h4;
        *reinterpret_cast<ushort4*>(ol + e) = l4;
    }
}

extern "C" void kernel_launch(void* const* d_in, const int* in_sizes, int n_in,
                              void* d_out, int out_size, void* d_ws, size_t ws_size,
                              hipStream_t stream)
{
    const float* x    = (const float*)d_in[0];
    const float* Wkqv = (const float*)d_in[1];
    const float* Wm1  = (const float*)d_in[2];
    const float* bm1  = (const float*)d_in[3];
    const float* Wm2  = (const float*)d_in[4];
    const float* bm2  = (const float*)d_in[5];
    const float* gng  = (const float*)d_in[6];
    const float* gnb  = (const float*)d_in[7];
    const float* Wf1  = (const float*)d_in[8];
    const float* bf1  = (const float*)d_in[9];
    const float* Wf2  = (const float*)d_in[10];
    const float* bf2  = (const float*)d_in[11];
    const float* lng  = (const float*)d_in[12];
    const float* lnb  = (const float*)d_in[13];

    // 16 MiB slots S0..S11, lifetime-colored; peak exactly 192 MiB.
    char* wsb = (char*)d_ws;
    const size_t MiB = 1024 * 1024;
    auto SL = [&](int i) { return wsb + (size_t)i * 16 * MiB; };

    float* hbuf   = (float*)SL(0);
    us* h_hi      = (us*)SL(2);
    us* h_lo      = (us*)SL(3);
    us* qk_hi     = (us*)SL(4);                 // [8192][2048] = 32 MiB
    us* qk_lo     = (us*)SL(6);
    float* vbuf   = (float*)SL(8);              // 32 MiB
    us* WtA_hi    = (us*)SL(10);                // [3072][1024] = 6 MiB
    us* WtA_lo    = (us*)(SL(10) + 6 * MiB);
    us* vT_hi     = (us*)SL(2);                 // [4][1024][2048] = 16 MiB
    us* vT_lo     = (us*)SL(3);
    us* sp_hi     = (us*)SL(8);                 // [4][2048][2048] = 32 MiB
    us* sp_lo     = (us*)SL(10);
    float* drec   = (float*)SL(4);              // [4][2048] = 32 KiB
    us* ret_hi    = (us*)SL(6);
    us* ret_lo    = (us*)SL(7);
    us* Wt1_hi    = (us*)SL(2);                 // [2048][1024] = 4 MiB
    us* Wt1_lo    = (us*)(SL(2) + 4 * MiB);
    float* m1     = (float*)SL(8);              // [8192][2048] = 64 MiB
    us* sw_hi     = (us*)SL(4);
    us* sw_lo     = (us*)SL(5);
    us* Wt2_hi    = (us*)SL(2);                 // [1024][1024] = 2 MiB
    us* Wt2_lo    = (us*)(SL(2) + 2 * MiB);
    float* m2     = (float*)SL(10);             // 32 MiB
    float* part   = (float*)SL(2);
    float* stats  = (float*)(SL(2) + 1 * MiB);
    float* ybuf   = (float*)SL(8);              // 32 MiB
    us* y_hi      = (us*)SL(4);
    us* y_lo      = (us*)SL(5);
    us* Wtf1_hi   = (us*)SL(6);                 // [2048][1024] = 4 MiB
    us* Wtf1_lo   = (us*)(SL(6) + 4 * MiB);
    us* f1_hi     = (us*)SL(10);                // [8192][2048] = 32 MiB
    us* f1_lo     = (us*)SL(2);
    us* Wtf2_hi   = (us*)SL(6);                 // [1024][2048] = 4 MiB
    us* Wtf2_lo   = (us*)(SL(6) + 4 * MiB);
    float* f2     = (float*)SL(4);              // 32 MiB

    for (int l = 0; l < Ll; ++l) {
        const float* h = (l == 0) ? x : hbuf;
        if (l == 0)
            split_k<<<8192, 256, 0, stream>>>(x, h_hi, h_lo);

        // ---- QKV ----------------------------------------------------------
        tsplit_k<<<dim3(3 * Dd / 32, Dd / 32, 1), 256, 0, stream>>>(
            Wkqv + (size_t)l * Dd * 3 * Dd, 0, WtA_hi, WtA_lo, 0, Dd, 3 * Dd);
        // cols 0:2048 -> [k | q] planes  (256x256 kernel, grid 8x32, SWZ)
        gemm3w<1, false, 0><<<dim3(8, 32), 512, 0, stream>>>(
            h_hi, h_lo, Dd, WtA_hi, WtA_lo, Dd, nullptr,
            nullptr, qk_hi, qk_lo, 2 * Dd, Dd);
        // cols 2048:3072 -> v fp32  (SWZ)
        gemm3<0, false, 0, false, false, false, true><<<dim3(8, 64, 1), 256, 0, stream>>>(
            h_hi, h_lo, Dd, 0,
            WtA_hi + (size_t)2 * Dd * Dd, WtA_lo + (size_t)2 * Dd * Dd, Dd, 0,
            nullptr, vbuf, nullptr, nullptr, Dd, 0, drec, Dd);
        tsplit_k<<<dim3(Dd / 32, Ss / 32, Bb), 256, 0, stream>>>(
            vbuf, (long)Ss * Dd, vT_hi, vT_lo, (long)Dd * Ss, Ss, Dd);

        // ---- retention ----------------------------------------------------
        // scores = tril(q k^T)/(32(1+sqrt(i))), written as scaled hi/lo planes
        gemm3<1, false, 0, true, false, false, false><<<dim3(16, 16, Bb), 256, 0, stream>>>(
            qk_hi + Dd, qk_lo + Dd, 2 * Dd, (long)Ss * 2 * Dd,    // q
            qk_hi,      qk_lo,      2 * Dd, (long)Ss * 2 * Dd,    // k
            nullptr, nullptr, sp_hi, sp_lo, Ss, (long)Ss * Ss, drec, Dd);
        denom_k<<<dim3(Ss, Bb), 256, 0, stream>>>(sp_hi, sp_lo, drec);
        // ret = (scores/denom) @ v  -> split planes
        gemm3<1, false, 0, false, true, true, false><<<dim3(8, 16, Bb), 256, 0, stream>>>(
            sp_hi, sp_lo, Ss, (long)Ss * Ss,
            vT_hi, vT_lo, Ss, (long)Dd * Ss,
            nullptr, nullptr, ret_hi, ret_lo, Dd, (long)Ss * Dd, drec, Ss);

        // ---- SwiGLU MLP ---------------------------------------------------
        tsplit_k<<<dim3(2 * Dd / 32, Dd / 32, 1), 256, 0, stream>>>(
            Wm1 + (size_t)l * Dd * 2 * Dd, 0, Wt1_hi, Wt1_lo, 0, Dd, 2 * Dd);
        gemm3w<0, true, 0><<<dim3(8, 32), 512, 0, stream>>>(
            ret_hi, ret_lo, Dd, Wt1_hi, Wt1_lo, Dd,
            bm1 + (size_t)l * 2 * Dd, m1, nullptr, nullptr, 2 * Dd, Dd);
        swiglu_k<<<8192, 256, 0, stream>>>(m1, sw_hi, sw_lo);
        tsplit_k<<<dim3(Dd / 32, Dd / 32, 1), 256, 0, stream>>>(
            Wm2 + (size_t)l * Dd * Dd, 0, Wt2_hi, Wt2_lo, 0, Dd, Dd);
        gemm3<0, true, 0, false, false, false, true><<<dim3(8, 64, 1), 256, 0, stream>>>(
            sw_hi, sw_lo, Dd, 0, Wt2_hi, Wt2_lo, Dd, 0,
            bm2 + (size_t)l * Dd, m2, nullptr, nullptr, Dd, 0, drec, Dd);

        // ---- GroupNorm + residual ----------------------------------------
        gn_part_k<<<dim3(256, Bb), 256, 0, stream>>>(m2, part);
        gn_final_k<<<Bb, 256, 0, stream>>>(part, stats);
        gn_apply_k<<<8192, 256, 0, stream>>>(
            m2, h, gng + (size_t)l * Dd, gnb + (size_t)l * Dd, stats,
            ybuf, y_hi, y_lo);

        // ---- FFN ----------------------------------------------------------
        tsplit_k<<<dim3(2 * Dd / 32, Dd / 32, 1), 256, 0, stream>>>(
            Wf1 + (size_t)l * Dd * 2 * Dd, 0, Wtf1_hi, Wtf1_lo, 0, Dd, 2 * Dd);
        gemm3w<1, true, 1><<<dim3(8, 32), 512, 0, stream>>>(
            y_hi, y_lo, Dd, Wtf1_hi, Wtf1_lo, Dd,
            bf1 + (size_t)l * 2 * Dd,
            nullptr, f1_hi, f1_lo, 2 * Dd, Dd);               // GELU fused
        tsplit_k<<<dim3(Dd / 32, 2 * Dd / 32, 1), 256, 0, stream>>>(
            Wf2 + (size_t)l * 2 * Dd * Dd, 0, Wtf2_hi, Wtf2_lo, 0, 2 * Dd, Dd);
        gemm3<0, true, 0, false, false, false, true><<<dim3(8, 64, 1), 256, 0, stream>>>(
            f1_hi, f1_lo, 2 * Dd, 0, Wtf2_hi, Wtf2_lo, 2 * Dd, 0,
            bf2 + (size_t)l * Dd, f2, nullptr, nullptr, Dd, 0, drec, 2 * Dd);

        // ---- LayerNorm ----------------------------------------------------
        if (l == Ll - 1)
            ln_k<false><<<BSm, 256, 0, stream>>>(
                f2, ybuf, lng + (size_t)l * Dd, lnb + (size_t)l * Dd,
                (float*)d_out, nullptr, nullptr);
        else
            ln_k<true><<<BSm, 256, 0, stream>>>(
                f2, ybuf, lng + (size_t)l * Dd, lnb + (size_t)l * Dd,
                hbuf, h_hi, h_lo);
    }
}